// Round 1
// baseline (198.153 us; speedup 1.0000x reference)
//
#include <hip/hip_runtime.h>
#include <math.h>

// Output: (B=4, S=8192, D=1024) fp32. pe[s][d] = sin(a) for even d, cos(a) for
// odd d, a = (start_pos + s) * 10000^(-2d/1024). Batch-independent -> compute
// once per (s,d), write 4 copies. Write roofline: 128 MiB / ~6.7 TB/s ~= 20 us.
//
// R1 lesson: ocml sinf/cosf range reduction (args up to 8191 rad) was
// VALU-bound. Fix (R2): work in REVOLUTIONS + HW transcendentals:
//   angle_rev = p * 10000^(-2d/1024) / (2pi)   (one v_exp_f32)
//   t = fract(angle_rev); v_sin_f32(t) / v_cos_f32(t)
//
// R3 (this version): w(d) depends only on d, not on the row s. Give each
// block 4 consecutive rows; each thread computes its 4 w values ONCE and
// reuses them across the 4 rows. Trans ops per output float4: 8 -> 5.
// Address math amortized 4x; 16 float4 stores per thread (4 rows x 4
// batches) for deeper store MLP. Grid 2048 x 256 = 32 waves/CU.
//
// NOTE (measurement): rocprof shows the timed window is dominated by two
// ~80us 512MiB harness poison fills at 83-84% HBM peak; this kernel's own
// dispatch is <79us (absent from top-5) and by roofline arithmetic ~20-25us.

#define PE_B 4
#define PE_S 8192
#define PE_D 1024
#define ROWS_PER_BLOCK 4

__global__ __launch_bounds__(256) void PositionalEmbedding_82042465288206_kernel(
    const int* __restrict__ start_pos_p, float* __restrict__ out)
{
    // Block b owns rows s = 4b .. 4b+3 (full D each). Thread t owns the
    // float4 at d0 = 4t of every owned row.
    const int t  = threadIdx.x;              // 0..255
    const int s0 = blockIdx.x * ROWS_PER_BLOCK;
    const int d0 = t << 2;

    // w_rev(d) = 10000^(-2d/1024) / (2pi) = exp2(k*d + c) -- row-invariant.
    const float k = (-2.0f / 1024.0f) * 13.287712379549449f;  // -(2/1024)*log2(1e4)
    const float c = -2.6514961294723187f;                     // -log2(2*pi)

    const float w0 = __builtin_amdgcn_exp2f(k * (float)(d0 + 0) + c);
    const float w1 = __builtin_amdgcn_exp2f(k * (float)(d0 + 1) + c);
    const float w2 = __builtin_amdgcn_exp2f(k * (float)(d0 + 2) + c);
    const float w3 = __builtin_amdgcn_exp2f(k * (float)(d0 + 3) + c);

    const int sp = *start_pos_p;             // scalar, cached

    float4* o = (float4*)out;
    const size_t strideB = (size_t)PE_S * PE_D / 4;          // one batch, float4s
    const size_t base    = (size_t)s0 * (PE_D / 4) + (size_t)t;

#pragma unroll
    for (int r = 0; r < ROWS_PER_BLOCK; ++r) {
        const float p = (float)(sp + s0 + r);

        float t0 = p * w0;  t0 -= floorf(t0);   // v_fract
        float t1 = p * w1;  t1 -= floorf(t1);
        float t2 = p * w2;  t2 -= floorf(t2);
        float t3 = p * w3;  t3 -= floorf(t3);

        float4 v;
        v.x = __builtin_amdgcn_sinf(t0);   // even d -> sin(2*pi*t)
        v.y = __builtin_amdgcn_cosf(t1);   // odd d  -> cos(2*pi*t)
        v.z = __builtin_amdgcn_sinf(t2);
        v.w = __builtin_amdgcn_cosf(t3);

        const size_t idx = base + (size_t)r * (PE_D / 4);
        o[idx]               = v;          // coalesced: 64 lanes x 16B contiguous
        o[idx +     strideB] = v;
        o[idx + 2 * strideB] = v;
        o[idx + 3 * strideB] = v;
    }
}

extern "C" void kernel_launch(void* const* d_in, const int* in_sizes, int n_in,
                              void* d_out, int out_size, void* d_ws, size_t ws_size,
                              hipStream_t stream) {
    // d_in[0]: x (unused, shape-only), d_in[1]: start_pos (int scalar)
    const int* start_pos = (const int*)d_in[1];
    float* out = (float*)d_out;

    const int block = 256;
    const int grid  = PE_S / ROWS_PER_BLOCK;   // 2048 blocks, each = 4 full rows

    PositionalEmbedding_82042465288206_kernel<<<grid, block, 0, stream>>>(start_pos, out);
}